// Round 17
// baseline (27.760 us; speedup 1.0000x reference)
//
#include <hip/hip_runtime.h>
#include <hip/hip_fp16.h>

#define BATCH  1024
#define NVARS  2048
#define N_OUT  4096

typedef float f32x4 __attribute__((ext_vector_type(4)));

__device__ __forceinline__ __half2 u2h2(unsigned u) {
    union { unsigned u; __half2 h; } c; c.u = u; return c.h;
}
__device__ __forceinline__ unsigned h22u(__half2 h) {
    union { unsigned u; __half2 h; } c; c.h = h; return c.u;
}
__device__ __forceinline__ void sel2sc(unsigned sel, unsigned& s, unsigned& c) {
    // half2 constants: 1.0h2 = 0x3C003C00, -1.0h2 = 0xBC00BC00
    c = (sel & 1u) ? 0x3C003C00u : 0u;
    s = (sel == 2u) ? 0x3C003C00u : (sel == 3u) ? 0xBC00BC00u : 0u;
}

// ---------------- kernel 1: T-flatten ONLY (once, deduplicated) ----------------
// T[i*8+m] = leafA | leafB<<16, leaf = sel<<11 | row. sel:0->0,1->1,2->x,3->1-x
__global__ __launch_bounds__(256) void tflat_kernel(
    const int2* __restrict__ idx0,
    const int2* __restrict__ idx1,
    const int2* __restrict__ idx2,
    const int2* __restrict__ idx3,
    unsigned* __restrict__ T)
{
    const int i = blockIdx.x * 256 + threadIdx.x;   // 16 blocks x 256 = 4096
    int2 p3 = idx3[i];
    int n = 0;
    #pragma unroll
    for (int t = 0; t < 2; ++t) {
        int2 p2 = idx2[t ? p3.y : p3.x];
        #pragma unroll
        for (int u = 0; u < 2; ++u) {
            int2 p1 = idx1[u ? p2.y : p2.x];
            #pragma unroll
            for (int v = 0; v < 2; ++v) {
                int2 p0 = idx0[v ? p1.y : p1.x];
                unsigned w = 0;
                #pragma unroll
                for (int e = 0; e < 2; ++e) {
                    int k = e ? p0.y : p0.x;
                    unsigned code;
                    if (k < 2) code = (unsigned)k << 11;
                    else       code = ((2u + (k & 1)) << 11) | ((unsigned)(k - 2) >> 1);
                    w |= code << (16 * e);
                }
                __builtin_nontemporal_store(w, &T[(size_t)i * 8 + n]);
                ++n;
            }
        }
    }
}

// ---------------- kernel 2: fused stage + single-pass compute + NT store --------
// 256 blocks x 1024 threads, 1 block/CU (128 KiB LDS). XCD k (= bx&7) owns
// windows 4k..4k+3 (x slice L2-resident, 8x reuse). Thread = (output ol,
// 16-col half h): ONE pass, T4 loads issued BEFORE staging (latency hidden
// under the stage burst), per-leaf address computed once feeding two adjacent
// ds_read_b128. Lane pairs store 128 B full lines, NT.
__global__ __launch_bounds__(1024) void knowledge_main(
    const float* __restrict__ x,
    const uint4* __restrict__ T4,     // 2 x uint4 per output (8 packed pair-words)
    float* __restrict__ out)
{
    __shared__ char lds[131072];      // window: row r at byte r*64 (32 fp16 cols)

    const int bx    = blockIdx.x;     // 256
    const int tid   = threadIdx.x;    // 0..1023
    const int xcd   = bx & 7;
    const int slot  = bx >> 3;        // 0..31
    const int w     = xcd * 4 + (slot & 3);  // window 0..31 (cols w*32..w*32+31)
    const int chunk = slot >> 2;      // 0..7 (512 outputs each)

    const int h  = tid & 1;           // 16-col half (bytes h*32..h*32+31 of row)
    const int ol = tid >> 1;          // output 0..511
    const int o  = chunk * 512 + ol;
    const int hb = h * 32;

    // ---- issue T loads FIRST: global latency hides under staging ----
    uint4 t0 = T4[(size_t)o * 2];
    uint4 t1 = T4[(size_t)o * 2 + 1];

    // ---- stage: x slice (2048 rows x 32 f32) -> LDS fp16, full-line reads ----
    {
        const float4* x4 = (const float4*)x;   // row stride 256 float4
        #pragma unroll
        for (int it = 0; it < 16; ++it) {
            const int u = it * 1024 + tid;     // (row, 16B-piece): 2048*8 units
            const int r = u >> 3, p = u & 7;
            float4 v = x4[(size_t)r * 256 + w * 8 + p];
            uint2 d;
            d.x = h22u(__floats2half2_rn(v.x, v.y));
            d.y = h22u(__floats2half2_rn(v.z, v.w));
            *(uint2*)(lds + r * 64 + p * 8) = d;
        }
    }
    __syncthreads();

    const unsigned tw[8] = {t0.x, t0.y, t0.z, t0.w, t1.x, t1.y, t1.z, t1.w};

    float accf[16];
    #pragma unroll
    for (int k = 0; k < 16; ++k) accf[k] = 0.f;

    #pragma unroll
    for (int a3 = 0; a3 < 2; ++a3) {                 // top SumLayer
        __half2 prod2[8];
        #pragma unroll
        for (int a2 = 0; a2 < 2; ++a2) {             // ProductLayer
            __half2 sum1[8];
            #pragma unroll
            for (int a1 = 0; a1 < 2; ++a1) {         // SumLayer
                const int m = a3 * 4 + a2 * 2 + a1;
                const unsigned wv = tw[m];
                const char* pA = lds + ((wv & 0x7FFu) << 6) + hb;
                const char* pB = lds + (((wv >> 16) & 0x7FFu) << 6) + hb;
                uint4 A0 = *(const uint4*)(pA);
                uint4 A1 = *(const uint4*)(pA + 16);
                uint4 B0 = *(const uint4*)(pB);
                uint4 B1 = *(const uint4*)(pB + 16);
                unsigned sa, ca, sb, cb;
                sel2sc((wv >> 11) & 3u, sa, ca);
                sel2sc((wv >> 27) & 3u, sb, cb);
                const unsigned aw[8] = {A0.x,A0.y,A0.z,A0.w,A1.x,A1.y,A1.z,A1.w};
                const unsigned bw[8] = {B0.x,B0.y,B0.z,B0.w,B1.x,B1.y,B1.z,B1.w};
                #pragma unroll
                for (int k = 0; k < 8; ++k) {
                    __half2 va = __hfma2(u2h2(aw[k]), u2h2(sa), u2h2(ca));
                    __half2 vb = __hfma2(u2h2(bw[k]), u2h2(sb), u2h2(cb));
                    __half2 pr = __hmul2(va, vb);    // leaf product
                    sum1[k] = (a1 == 0) ? pr : __hadd2(sum1[k], pr);
                }
            }
            #pragma unroll
            for (int k = 0; k < 8; ++k)
                prod2[k] = (a2 == 0) ? sum1[k] : __hmul2(prod2[k], sum1[k]);
        }
        #pragma unroll
        for (int k = 0; k < 8; ++k) {                // top sum in f32
            float2 pf = __half22float2(prod2[k]);
            accf[2 * k]     += pf.x;
            accf[2 * k + 1] += pf.y;
        }
    }

    // lanes (2i, 2i+1) cover output row o's 32 cols = 128 B full line
    float* dst = out + (size_t)o * BATCH + w * 32 + h * 16;
    f32x4 o0 = {accf[0],  accf[1],  accf[2],  accf[3]};
    f32x4 o1 = {accf[4],  accf[5],  accf[6],  accf[7]};
    f32x4 o2 = {accf[8],  accf[9],  accf[10], accf[11]};
    f32x4 o3 = {accf[12], accf[13], accf[14], accf[15]};
    __builtin_nontemporal_store(o0, reinterpret_cast<f32x4*>(dst));
    __builtin_nontemporal_store(o1, reinterpret_cast<f32x4*>(dst) + 1);
    __builtin_nontemporal_store(o2, reinterpret_cast<f32x4*>(dst) + 2);
    __builtin_nontemporal_store(o3, reinterpret_cast<f32x4*>(dst) + 3);
}

// ---------------- fallback (round-1 kernel) if ws too small ----------------
__device__ __forceinline__ float Hval(int k, const float* __restrict__ x, int b) {
    if (k < 2) return (float)k;
    float v = x[((k - 2) >> 1) * BATCH + b];
    return (k & 1) ? 1.0f - v : v;
}

__global__ __launch_bounds__(256) void knowledge_fused_kernel(
    const float* __restrict__ x,
    const int2* __restrict__ idx0,
    const int2* __restrict__ idx1,
    const int2* __restrict__ idx2,
    const int2* __restrict__ idx3,
    float* __restrict__ out)
{
    const int i = blockIdx.x;
    const int b = blockIdx.y * blockDim.x + threadIdx.x;
    const int2 p3 = idx3[i];
    float acc3 = 0.0f;
    #pragma unroll
    for (int t = 0; t < 2; ++t) {
        const int2 p2 = idx2[t ? p3.y : p3.x];
        float prod2 = 1.0f;
        #pragma unroll
        for (int u = 0; u < 2; ++u) {
            const int2 p1 = idx1[u ? p2.y : p2.x];
            float sum1 = 0.0f;
            #pragma unroll
            for (int v = 0; v < 2; ++v) {
                const int2 p0 = idx0[v ? p1.y : p1.x];
                sum1 += Hval(p0.x, x, b) * Hval(p0.y, x, b);
            }
            prod2 *= sum1;
        }
        acc3 += prod2;
    }
    out[(size_t)i * BATCH + b] = acc3;
}

extern "C" void kernel_launch(void* const* d_in, const int* in_sizes, int n_in,
                              void* d_out, int out_size, void* d_ws, size_t ws_size,
                              hipStream_t stream) {
    const float* x    = (const float*)d_in[0];
    const int2*  idx0 = (const int2*)d_in[1];
    const int2*  idx1 = (const int2*)d_in[2];
    const int2*  idx2 = (const int2*)d_in[3];
    const int2*  idx3 = (const int2*)d_in[4];
    float* out = (float*)d_out;

    const size_t t_bytes = (size_t)N_OUT * 8 * sizeof(unsigned);   // 128 KB
    if (ws_size >= t_bytes) {
        unsigned* T = (unsigned*)d_ws;
        tflat_kernel<<<16, 256, 0, stream>>>(idx0, idx1, idx2, idx3, T);
        knowledge_main<<<256, 1024, 0, stream>>>(x, (const uint4*)T, out);
    } else {
        dim3 grid(N_OUT, BATCH / 256);
        knowledge_fused_kernel<<<grid, 256, 0, stream>>>(x, idx0, idx1, idx2, idx3, out);
    }
}

// Round 18
// 19.951 us; speedup vs baseline: 1.3915x; 1.3915x over previous
//
#include <hip/hip_runtime.h>
#include <hip/hip_fp16.h>

#define BATCH  1024
#define NVARS  2048
#define N_OUT  4096

typedef float f32x4 __attribute__((ext_vector_type(4)));

__device__ __forceinline__ __half2 u2h2(unsigned u) {
    union { unsigned u; __half2 h; } c; c.u = u; return c.h;
}
__device__ __forceinline__ unsigned h22u(__half2 h) {
    union { unsigned u; __half2 h; } c; c.h = h; return c.u;
}
__device__ __forceinline__ void sel2sc(unsigned sel, unsigned& s, unsigned& c) {
    // half2 constants: 1.0h2 = 0x3C003C00, -1.0h2 = 0xBC00BC00
    c = (sel & 1u) ? 0x3C003C00u : 0u;
    s = (sel == 2u) ? 0x3C003C00u : (sel == 3u) ? 0xBC00BC00u : 0u;
}

// ---------------- kernel 1: T-flatten ONLY (once, deduplicated) ----------------
// T[i*8+m] = leafA | leafB<<16, leaf = sel<<11 | row. sel:0->0,1->1,2->x,3->1-x
__global__ __launch_bounds__(256) void tflat_kernel(
    const int2* __restrict__ idx0,
    const int2* __restrict__ idx1,
    const int2* __restrict__ idx2,
    const int2* __restrict__ idx3,
    unsigned* __restrict__ T)
{
    const int i = blockIdx.x * 256 + threadIdx.x;   // 16 blocks x 256 = 4096
    int2 p3 = idx3[i];
    int n = 0;
    #pragma unroll
    for (int t = 0; t < 2; ++t) {
        int2 p2 = idx2[t ? p3.y : p3.x];
        #pragma unroll
        for (int u = 0; u < 2; ++u) {
            int2 p1 = idx1[u ? p2.y : p2.x];
            #pragma unroll
            for (int v = 0; v < 2; ++v) {
                int2 p0 = idx0[v ? p1.y : p1.x];
                unsigned w = 0;
                #pragma unroll
                for (int e = 0; e < 2; ++e) {
                    int k = e ? p0.y : p0.x;
                    unsigned code;
                    if (k < 2) code = (unsigned)k << 11;
                    else       code = ((2u + (k & 1)) << 11) | ((unsigned)(k - 2) >> 1);
                    w |= code << (16 * e);
                }
                __builtin_nontemporal_store(w, &T[(size_t)i * 8 + n]);
                ++n;
            }
        }
    }
}

// ---------------- kernel 2: fused stage + compute + NT store, SPLIT-HALF LDS ----
// 256 blocks x 1024 threads, 1 block/CU (128 KiB LDS). XCD k (= bx&7) owns
// windows 4k..4k+3 (x slice L2-resident, 8x reuse).
// LDS layout: two 64 KiB halves, row stride 32 B:
//   byte(r, col-piece q) = (q>>1)*65536 + r*32 + (q&1)*16   (q = 16B piece 0..3)
// -> row base bank = (r*8)%32: random rows spread uniformly over all 32 banks
//    (row-stride-64 layouts pin bases to {0,16} -> 2-8x bank aliasing, the R17
//    regression and the R13/R16 hidden cost).
// Thread = (output ol, cg 0..3); cg reads piece cg -> hoff = (cg>>1)*65536 +
// (cg&1)*16, addr = hoff + r*32. 2 passes x 256 outputs. Full-line NT stores.
__global__ __launch_bounds__(1024) void knowledge_main(
    const float* __restrict__ x,
    const uint4* __restrict__ T4,     // 2 x uint4 per output (8 packed pair-words)
    float* __restrict__ out)
{
    __shared__ char lds[131072];

    const int bx    = blockIdx.x;     // 256
    const int tid   = threadIdx.x;    // 0..1023
    const int xcd   = bx & 7;
    const int slot  = bx >> 3;        // 0..31
    const int w     = xcd * 4 + (slot & 3);  // window 0..31 (cols w*32..w*32+31)
    const int chunk = slot >> 2;      // 0..7 (512 outputs each)

    const int cg  = tid & 3;          // col-piece 0..3 (8 cols = 16 B fp16)
    const int ol  = tid >> 2;         // output-in-pass 0..255
    const int hoff= (cg >> 1) * 65536 + (cg & 1) * 16;  // thread-const LDS offset

    // ---- issue pass-0 T loads FIRST: latency hides under staging ----
    int o = chunk * 512 + ol;
    uint4 t0 = T4[(size_t)o * 2];
    uint4 t1 = T4[(size_t)o * 2 + 1];

    // ---- stage: x slice (2048 rows x 32 f32) -> split-half LDS fp16 ----
    {
        const float4* x4 = (const float4*)x;   // row stride 256 float4
        #pragma unroll
        for (int it = 0; it < 16; ++it) {
            const int u = it * 1024 + tid;     // (row, 8B-piece p): 2048*8 units
            const int r = u >> 3, p = u & 7;
            float4 v = x4[(size_t)r * 256 + w * 8 + p];
            uint2 d;
            d.x = h22u(__floats2half2_rn(v.x, v.y));
            d.y = h22u(__floats2half2_rn(v.z, v.w));
            // fp16 row bytes 8p..8p+7 -> half = p>>2, within-half = (p&3)*8
            *(uint2*)(lds + ((p & 4) << 14) + r * 32 + (p & 3) * 8) = d;
        }
    }
    __syncthreads();

    #pragma unroll 1
    for (int pass = 0; pass < 2; ++pass) {
        const unsigned tw[8] = {t0.x, t0.y, t0.z, t0.w, t1.x, t1.y, t1.z, t1.w};

        // prefetch next pass's T while this pass computes
        if (pass == 0) {
            t0 = T4[(size_t)(o + 256) * 2];
            t1 = T4[(size_t)(o + 256) * 2 + 1];
        }

        float accf[8];
        #pragma unroll
        for (int k = 0; k < 8; ++k) accf[k] = 0.f;

        #pragma unroll
        for (int a3 = 0; a3 < 2; ++a3) {                 // top SumLayer
            __half2 prod2[4];
            #pragma unroll
            for (int a2 = 0; a2 < 2; ++a2) {             // ProductLayer
                __half2 sum1[4];
                #pragma unroll
                for (int a1 = 0; a1 < 2; ++a1) {         // SumLayer
                    const int m = a3 * 4 + a2 * 2 + a1;
                    const unsigned wv = tw[m];
                    uint4 A = *(const uint4*)(lds + ((wv & 0x7FFu) << 5) + hoff);
                    uint4 B = *(const uint4*)(lds + (((wv >> 16) & 0x7FFu) << 5) + hoff);
                    unsigned sa, ca, sb, cb;
                    sel2sc((wv >> 11) & 3u, sa, ca);
                    sel2sc((wv >> 27) & 3u, sb, cb);
                    const unsigned aw[4] = {A.x, A.y, A.z, A.w};
                    const unsigned bw[4] = {B.x, B.y, B.z, B.w};
                    #pragma unroll
                    for (int k = 0; k < 4; ++k) {
                        __half2 va = __hfma2(u2h2(aw[k]), u2h2(sa), u2h2(ca));
                        __half2 vb = __hfma2(u2h2(bw[k]), u2h2(sb), u2h2(cb));
                        __half2 pr = __hmul2(va, vb);    // leaf product
                        sum1[k] = (a1 == 0) ? pr : __hadd2(sum1[k], pr);
                    }
                }
                #pragma unroll
                for (int k = 0; k < 4; ++k)
                    prod2[k] = (a2 == 0) ? sum1[k] : __hmul2(prod2[k], sum1[k]);
            }
            #pragma unroll
            for (int k = 0; k < 4; ++k) {                // top sum in f32
                float2 pf = __half22float2(prod2[k]);
                accf[2 * k]     += pf.x;
                accf[2 * k + 1] += pf.y;
            }
        }

        // lanes 4i..4i+3 cover cols w*32..w*32+31 = 128 B contiguous (full line)
        float* dst = out + (size_t)o * BATCH + w * 32 + cg * 8;
        f32x4 o0 = {accf[0], accf[1], accf[2], accf[3]};
        f32x4 o1 = {accf[4], accf[5], accf[6], accf[7]};
        __builtin_nontemporal_store(o0, reinterpret_cast<f32x4*>(dst));
        __builtin_nontemporal_store(o1, reinterpret_cast<f32x4*>(dst) + 1);

        o += 256;
    }
}

// ---------------- fallback (round-1 kernel) if ws too small ----------------
__device__ __forceinline__ float Hval(int k, const float* __restrict__ x, int b) {
    if (k < 2) return (float)k;
    float v = x[((k - 2) >> 1) * BATCH + b];
    return (k & 1) ? 1.0f - v : v;
}

__global__ __launch_bounds__(256) void knowledge_fused_kernel(
    const float* __restrict__ x,
    const int2* __restrict__ idx0,
    const int2* __restrict__ idx1,
    const int2* __restrict__ idx2,
    const int2* __restrict__ idx3,
    float* __restrict__ out)
{
    const int i = blockIdx.x;
    const int b = blockIdx.y * blockDim.x + threadIdx.x;
    const int2 p3 = idx3[i];
    float acc3 = 0.0f;
    #pragma unroll
    for (int t = 0; t < 2; ++t) {
        const int2 p2 = idx2[t ? p3.y : p3.x];
        float prod2 = 1.0f;
        #pragma unroll
        for (int u = 0; u < 2; ++u) {
            const int2 p1 = idx1[u ? p2.y : p2.x];
            float sum1 = 0.0f;
            #pragma unroll
            for (int v = 0; v < 2; ++v) {
                const int2 p0 = idx0[v ? p1.y : p1.x];
                sum1 += Hval(p0.x, x, b) * Hval(p0.y, x, b);
            }
            prod2 *= sum1;
        }
        acc3 += prod2;
    }
    out[(size_t)i * BATCH + b] = acc3;
}

extern "C" void kernel_launch(void* const* d_in, const int* in_sizes, int n_in,
                              void* d_out, int out_size, void* d_ws, size_t ws_size,
                              hipStream_t stream) {
    const float* x    = (const float*)d_in[0];
    const int2*  idx0 = (const int2*)d_in[1];
    const int2*  idx1 = (const int2*)d_in[2];
    const int2*  idx2 = (const int2*)d_in[3];
    const int2*  idx3 = (const int2*)d_in[4];
    float* out = (float*)d_out;

    const size_t t_bytes = (size_t)N_OUT * 8 * sizeof(unsigned);   // 128 KB
    if (ws_size >= t_bytes) {
        unsigned* T = (unsigned*)d_ws;
        tflat_kernel<<<16, 256, 0, stream>>>(idx0, idx1, idx2, idx3, T);
        knowledge_main<<<256, 1024, 0, stream>>>(x, (const uint4*)T, out);
    } else {
        dim3 grid(N_OUT, BATCH / 256);
        knowledge_fused_kernel<<<grid, 256, 0, stream>>>(x, idx0, idx1, idx2, idx3, out);
    }
}